// Round 3
// baseline (343.374 us; speedup 1.0000x reference)
//
#include <hip/hip_runtime.h>
#include <hip/hip_bf16.h>

#define B_    256
#define NKV   128
#define NQ    512
#define CDIM  192
#define QCDIM 96
#define NH    6
#define DH    32
#define SCALE 0.17677669529663687f

typedef __hip_bfloat16 bf16;
typedef __attribute__((ext_vector_type(8))) short s16x8;
typedef __attribute__((ext_vector_type(4))) float f32x4;
#define MFMA16(a, b, c) __builtin_amdgcn_mfma_f32_16x16x32_bf16(a, b, c, 0, 0, 0)

// ---- workspace layout (bytes) ----
#define OFF_BIAS  0                       // fp32 [NH][512][128] = 1,572,864
#define OFF_WKVT  1572864                 // bf16 [384][192]     = 147,456  (w_kv^T)
#define OFF_WQT   (OFF_WKVT + 147456)     // bf16 [192][96]      = 36,864   (w_q^T * scale)
#define OFF_WPT   (OFF_WQT + 36864)       // bf16 [96][192]      = 36,864   (w_proj^T)
#define OFF_KP    (OFF_WPT + 36864)       // bf16 [B_][128][192] = 12,582,912  K' row-major
#define OFF_VT    (OFF_KP + 12582912)     // bf16 [B_][192][128] = 12,582,912  V' transposed
// total ~27 MB (<= 52.4 MB known-safe ws)

__global__ __launch_bounds__(256)
void precomp_bias(const float* __restrict__ bias_table, const int* __restrict__ rel_index,
                  float* __restrict__ biasM)
{
    const int i = blockIdx.x * 256 + threadIdx.x;   // NH*NQ*NKV = 393216
    const int h   = i >> 16;                        // NQ*NKV = 65536
    const int rem = i & 65535;
    biasM[i] = bias_table[rel_index[rem] * NH + h];
}

__global__ __launch_bounds__(256)
void precomp_w(const float* __restrict__ w_kv, const float* __restrict__ w_q,
               const float* __restrict__ w_proj,
               bf16* __restrict__ wkvT, bf16* __restrict__ wqT, bf16* __restrict__ wpT)
{
    const int i = blockIdx.x * 256 + threadIdx.x;   // 110592 total
    if (i < 384 * CDIM) {                           // 73728: wkvT[n][k] = w_kv[k][n]
        const int n = i / CDIM, k = i % CDIM;
        wkvT[i] = __float2bfloat16(w_kv[k * (2 * CDIM) + n]);
    } else if (i < 384 * CDIM + CDIM * QCDIM) {     // 18432: wqT[n][k] = w_q[k][n]*scale
        const int i2 = i - 384 * CDIM;
        const int n = i2 / QCDIM, k = i2 % QCDIM;
        wqT[i2] = __float2bfloat16(w_q[k * CDIM + n] * SCALE);
    } else {                                        // 18432: wpT[n][k] = w_proj[k][n]
        const int i3 = i - 384 * CDIM - CDIM * QCDIM;
        const int n = i3 / CDIM, k = i3 % CDIM;
        wpT[i3] = __float2bfloat16(w_proj[k * QCDIM + n]);
    }
}

// Per-batch: K',V' (all heads) = kv_b @ w_kv + b_kv -> ws bf16.
__global__ __launch_bounds__(512)
void proj_kv(const float* __restrict__ kv, const float* __restrict__ b_kv,
             const bf16* __restrict__ wkvT, bf16* __restrict__ Kp, bf16* __restrict__ VTp)
{
    __shared__ __align__(16) bf16 sA[128 * 200];
    const int b = blockIdx.x, t = threadIdx.x;
    const int w = t >> 6, lane = t & 63, quad = lane >> 4, l16 = lane & 15;
    const f32x4 ZV = {0.f, 0.f, 0.f, 0.f};

    for (int f = t; f < 6144; f += 512) {           // 128 rows x 48 float4
        const int r = f / 48, c4 = f % 48;
        const float4 v = *(const float4*)&kv[((size_t)b * NKV + r) * CDIM + c4 * 4];
        __align__(8) bf16 tmp[4] = {__float2bfloat16(v.x), __float2bfloat16(v.y),
                                    __float2bfloat16(v.z), __float2bfloat16(v.w)};
        *(uint2*)&sA[r * 200 + c4 * 4] = *(uint2*)tmp;
    }
    __syncthreads();

    f32x4 acc[24];
    #pragma unroll
    for (int i = 0; i < 24; ++i) acc[i] = ZV;
    for (int kk = 0; kk < 6; ++kk) {
        const s16x8 a = *(const s16x8*)&sA[(w * 16 + l16) * 200 + kk * 32 + quad * 8];
        #pragma unroll
        for (int nt = 0; nt < 24; ++nt) {
            const s16x8 bb = *(const s16x8*)&wkvT[(nt * 16 + l16) * CDIM + kk * 32 + quad * 8];
            acc[nt] = MFMA16(a, bb, acc[nt]);
        }
    }
    // epilogue: +bias; nt<12 -> K' row-major; nt>=12 -> V' transposed
    #pragma unroll
    for (int nt = 0; nt < 24; ++nt) {
        const int col = nt * 16 + l16;
        const float bias = b_kv[col];
        if (nt < 12) {
            #pragma unroll
            for (int r = 0; r < 4; ++r) {
                const int m = w * 16 + quad * 4 + r;
                Kp[((size_t)b * NKV + m) * CDIM + col] = __float2bfloat16(acc[nt][r] + bias);
            }
        } else {
            const int j = col - CDIM;
            __align__(8) bf16 tmp[4];
            #pragma unroll
            for (int r = 0; r < 4; ++r) tmp[r] = __float2bfloat16(acc[nt][r] + bias);
            *(uint2*)&VTp[((size_t)b * CDIM + j) * NKV + w * 16 + quad * 4] = *(uint2*)tmp;
        }
    }
}

// Per (batch, q-chunk of 128): q-proj + S + softmax + PV + final projection.
__global__ __launch_bounds__(512, 4)
void attn_fused(const float* __restrict__ q, const float* __restrict__ b_q,
                const float* __restrict__ b_proj, const char* __restrict__ wsro,
                float* __restrict__ out)
{
    __shared__ __align__(16) char smem[61440];
    bf16* sQin = (bf16*)smem;                 // [128][104]  26,624 B
    bf16* sP   = (bf16*)(smem + 26624);       // per-wave [16][136] patches, 34,816 B

    const int b = blockIdx.x, qc = blockIdx.y;
    const int t = threadIdx.x;
    const int w = t >> 6, lane = t & 63, quad = lane >> 4, l16 = lane & 15;
    const f32x4 ZV = {0.f, 0.f, 0.f, 0.f};

    const float* biasM = (const float*)(wsro + OFF_BIAS);
    const bf16*  wqT   = (const bf16*)(wsro + OFF_WQT);
    const bf16*  wpT   = (const bf16*)(wsro + OFF_WPT);
    const bf16*  Kp    = (const bf16*)(wsro + OFF_KP) + (size_t)b * NKV * CDIM;
    const bf16*  VTp   = (const bf16*)(wsro + OFF_VT) + (size_t)b * CDIM * NKV;

    // stage q chunk fp32->bf16 (the ONLY cross-wave LDS use)
    for (int f = t; f < 3072; f += 512) {     // 128 rows x 24 float4
        const int r = f / 24, c4 = f % 24;
        const float4 v = *(const float4*)&q[((size_t)b * NQ + qc * 128 + r) * QCDIM + c4 * 4];
        __align__(8) bf16 tmp[4] = {__float2bfloat16(v.x), __float2bfloat16(v.y),
                                    __float2bfloat16(v.z), __float2bfloat16(v.w)};
        *(uint2*)&sQin[r * 104 + c4 * 4] = *(uint2*)tmp;
    }
    __syncthreads();

    bf16* myP = sP + w * 16 * 136;            // wave-private patch

    f32x4 outacc[6];
    #pragma unroll
    for (int i = 0; i < 6; ++i) outacc[i] = ZV;

    for (int h = 0; h < NH; ++h) {
        // (a) Q'_h = q_chunk @ wqT[h*32..+32] (pre-scaled); +b_q*scale -> patch
        f32x4 qacc[2];
        qacc[0] = ZV; qacc[1] = ZV;
        #pragma unroll
        for (int kk = 0; kk < 3; ++kk) {
            const s16x8 a = *(const s16x8*)&sQin[(w * 16 + l16) * 104 + kk * 32 + quad * 8];
            #pragma unroll
            for (int tl = 0; tl < 2; ++tl) {
                const s16x8 bb = *(const s16x8*)&wqT[(h * DH + tl * 16 + l16) * QCDIM + kk * 32 + quad * 8];
                qacc[tl] = MFMA16(a, bb, qacc[tl]);
            }
        }
        #pragma unroll
        for (int tl = 0; tl < 2; ++tl) {
            const float bq = b_q[h * DH + tl * 16 + l16] * SCALE;
            #pragma unroll
            for (int r = 0; r < 4; ++r)
                myP[(quad * 4 + r) * 136 + tl * 16 + l16] = __float2bfloat16(qacc[tl][r] + bq);
        }
        __builtin_amdgcn_wave_barrier();

        // (b) S = Q'_h K'_h^T : K' B-frags direct from global (L2)
        const s16x8 aQ = *(const s16x8*)&myP[l16 * 136 + quad * 8];
        f32x4 sacc[8];
        #pragma unroll
        for (int tl = 0; tl < 8; ++tl) {
            const s16x8 bb = *(const s16x8*)&Kp[(size_t)(tl * 16 + l16) * CDIM + h * DH + quad * 8];
            sacc[tl] = MFMA16(aQ, bb, ZV);
        }
        __builtin_amdgcn_wave_barrier();

        // (c) +bias, softmax -> P into patch
        #pragma unroll
        for (int r = 0; r < 4; ++r) {
            const int qrow = qc * 128 + w * 16 + quad * 4 + r;
            const float* brow = biasM + ((size_t)h * NQ + qrow) * NKV + l16;
            float v[8];
            float mx = -1e30f;
            #pragma unroll
            for (int tl = 0; tl < 8; ++tl) {
                v[tl] = sacc[tl][r] + brow[tl * 16];
                mx = fmaxf(mx, v[tl]);
            }
            #pragma unroll
            for (int off = 1; off < 16; off <<= 1) mx = fmaxf(mx, __shfl_xor(mx, off));
            float sum = 0.f;
            #pragma unroll
            for (int tl = 0; tl < 8; ++tl) { v[tl] = __expf(v[tl] - mx); sum += v[tl]; }
            #pragma unroll
            for (int off = 1; off < 16; off <<= 1) sum += __shfl_xor(sum, off);
            const float inv = 1.f / sum;
            #pragma unroll
            for (int tl = 0; tl < 8; ++tl)
                myP[(quad * 4 + r) * 136 + tl * 16 + l16] = __float2bfloat16(v[tl] * inv);
        }
        __builtin_amdgcn_wave_barrier();

        // (d) O_h = P V'_h : V'^T B-frags direct from global (L2)
        f32x4 oacc[2];
        oacc[0] = ZV; oacc[1] = ZV;
        #pragma unroll
        for (int kk = 0; kk < 4; ++kk) {
            const s16x8 aP = *(const s16x8*)&myP[l16 * 136 + kk * 32 + quad * 8];
            #pragma unroll
            for (int tl = 0; tl < 2; ++tl) {
                const s16x8 bb = *(const s16x8*)&VTp[(size_t)(h * DH + tl * 16 + l16) * NKV + kk * 32 + quad * 8];
                oacc[tl] = MFMA16(aP, bb, oacc[tl]);
            }
        }
        __builtin_amdgcn_wave_barrier();

        // (e) O_h -> patch, then out += O_h @ w_proj[h*32..+32, :]
        #pragma unroll
        for (int tl = 0; tl < 2; ++tl)
            #pragma unroll
            for (int r = 0; r < 4; ++r)
                myP[(quad * 4 + r) * 136 + tl * 16 + l16] = __float2bfloat16(oacc[tl][r]);
        __builtin_amdgcn_wave_barrier();

        const s16x8 aO = *(const s16x8*)&myP[l16 * 136 + quad * 8];
        #pragma unroll
        for (int tn = 0; tn < 6; ++tn) {
            const s16x8 bb = *(const s16x8*)&wpT[(tn * 16 + l16) * CDIM + h * DH + quad * 8];
            outacc[tn] = MFMA16(aO, bb, outacc[tn]);
        }
        __builtin_amdgcn_wave_barrier();
    }

    // epilogue: +b_proj, fp32 out
    #pragma unroll
    for (int tn = 0; tn < 6; ++tn) {
        const float bp = b_proj[tn * 16 + l16];
        #pragma unroll
        for (int r = 0; r < 4; ++r)
            out[((size_t)b * NQ + qc * 128 + w * 16 + quad * 4 + r) * QCDIM + tn * 16 + l16]
                = outacc[tn][r] + bp;
    }
}

extern "C" void kernel_launch(void* const* d_in, const int* in_sizes, int n_in,
                              void* d_out, int out_size, void* d_ws, size_t ws_size,
                              hipStream_t stream)
{
    const float* kv       = (const float*)d_in[0];
    const float* q        = (const float*)d_in[1];
    const float* w_kv     = (const float*)d_in[2];
    const float* b_kv     = (const float*)d_in[3];
    const float* w_q      = (const float*)d_in[4];
    const float* b_q      = (const float*)d_in[5];
    const float* w_proj   = (const float*)d_in[6];
    const float* b_proj   = (const float*)d_in[7];
    const float* bias_tab = (const float*)d_in[8];
    const int*   rel_idx  = (const int*)d_in[9];
    char* ws = (char*)d_ws;

    precomp_bias<<<1536, 256, 0, stream>>>(bias_tab, rel_idx, (float*)(ws + OFF_BIAS));
    precomp_w<<<432, 256, 0, stream>>>(w_kv, w_q, w_proj,
                                       (bf16*)(ws + OFF_WKVT), (bf16*)(ws + OFF_WQT),
                                       (bf16*)(ws + OFF_WPT));
    proj_kv<<<B_, 512, 0, stream>>>(kv, b_kv, (const bf16*)(ws + OFF_WKVT),
                                    (bf16*)(ws + OFF_KP), (bf16*)(ws + OFF_VT));
    attn_fused<<<dim3(B_, 4), 512, 0, stream>>>(q, b_q, b_proj, (const char*)ws,
                                                (float*)d_out);
}

// Round 4
// 285.655 us; speedup vs baseline: 1.2021x; 1.2021x over previous
//
#include <hip/hip_runtime.h>
#include <hip/hip_bf16.h>

#define B_    256
#define NKV   128
#define NQ    512
#define CDIM  192
#define QCDIM 96
#define NH    6
#define DH    32
#define SCALE 0.17677669529663687f

typedef __hip_bfloat16 bf16;
typedef __attribute__((ext_vector_type(8))) short s16x8;
typedef __attribute__((ext_vector_type(4))) float f32x4;
#define MFMA16(a, b, c) __builtin_amdgcn_mfma_f32_16x16x32_bf16(a, b, c, 0, 0, 0)

// ---- workspace layout (bytes). All tensors ending in F are MFMA-fragment-
// ordered: [...frag...][lane(64)][8 bf16] so one wave reads one fragment as a
// single coalesced 16 B/lane global_load_dwordx4. ----
#define OFF_BIAS  0                        // fp32 [NH][512][128]        = 1,572,864
#define OFF_WKVF  1572864                  // bf16 [24][6][64][8]        = 147,456
#define OFF_WQF   (OFF_WKVF + 147456)      // bf16 [6][2][3][64][8]      = 36,864 (pre-scaled)
#define OFF_WPF   (OFF_WQF + 36864)        // bf16 [6][6][64][8]         = 36,864
#define OFF_KF    (OFF_WPF + 36864)        // bf16 [B_][6][8][64][8]     = 12,582,912
#define OFF_VF    (OFF_KF + 12582912)      // bf16 [B_][6][2][4][64][8]  = 12,582,912
#define OFF_QF    (OFF_VF + 12582912)      // bf16 [B_][32][3][64][8]    = 25,165,824
// total 52,125,696 B

__global__ __launch_bounds__(256)
void precomp_bias(const float* __restrict__ bias_table, const int* __restrict__ rel_index,
                  float* __restrict__ biasM)
{
    const int i = blockIdx.x * 256 + threadIdx.x;   // NH*NQ*NKV = 393216
    const int h   = i >> 16;
    const int rem = i & 65535;
    biasM[i] = bias_table[rel_index[rem] * NH + h];
}

// Weights -> bf16 fragment order (B-operand layout: n = base+l16, k = quad*8+j)
__global__ __launch_bounds__(256)
void precomp_w(const float* __restrict__ w_kv, const float* __restrict__ w_q,
               const float* __restrict__ w_proj,
               bf16* __restrict__ wkvF, bf16* __restrict__ wqF, bf16* __restrict__ wpF)
{
    const int i = blockIdx.x * 256 + threadIdx.x;   // 110592 total
    if (i < 73728) {                                // wkvF[nt24][kk6][lane][j]
        const int j = i & 7, lane = (i >> 3) & 63, kk = (i >> 9) % 6, nt = i / 3072;
        const int quad = lane >> 4, l16 = lane & 15;
        const int n = nt * 16 + l16, k = kk * 32 + quad * 8 + j;
        wkvF[i] = __float2bfloat16(w_kv[k * (2 * CDIM) + n]);
    } else if (i < 92160) {                         // wqF[h][tl2][kk3][lane][j]
        const int i2 = i - 73728;
        const int j = i2 & 7, lane = (i2 >> 3) & 63, kk = (i2 >> 9) % 3,
                  tl = (i2 / 1536) & 1, h = i2 / 3072;
        const int quad = lane >> 4, l16 = lane & 15;
        const int n = h * DH + tl * 16 + l16, k = kk * 32 + quad * 8 + j;
        wqF[i2] = __float2bfloat16(w_q[k * CDIM + n] * SCALE);
    } else {                                        // wpF[h][tn6][lane][j]
        const int i3 = i - 92160;
        const int j = i3 & 7, lane = (i3 >> 3) & 63, tn = (i3 >> 9) % 6, h = i3 / 3072;
        const int quad = lane >> 4, l16 = lane & 15;
        wpF[i3] = __float2bfloat16(w_proj[(h * DH + quad * 8 + j) * QCDIM + tn * 16 + l16]);
    }
}

// q fp32 -> bf16 A-fragment order: qF[b][rowblk32][kk3][lane][8],
// A[m=l16][k=quad*8+j], k in [0,96)
__global__ __launch_bounds__(256)
void repack_q(const float* __restrict__ q, bf16* __restrict__ qF)
{
    const int g = blockIdx.x * 256 + threadIdx.x;   // 1,572,864 groups
    const int lane = g & 63, kk = (g >> 6) % 3, rowblk = (g >> 6) / 3 % 32, b = g / 6144;
    const int quad = lane >> 4, l16 = lane & 15;
    const float* src = &q[((size_t)b * NQ + rowblk * 16 + l16) * QCDIM + kk * 32 + quad * 8];
    const float4 v0 = *(const float4*)src;
    const float4 v1 = *(const float4*)(src + 4);
    __align__(16) bf16 tmp[8] = {
        __float2bfloat16(v0.x), __float2bfloat16(v0.y), __float2bfloat16(v0.z),
        __float2bfloat16(v0.w), __float2bfloat16(v1.x), __float2bfloat16(v1.y),
        __float2bfloat16(v1.z), __float2bfloat16(v1.w)};
    *(uint4*)&qF[(size_t)g * 8] = *(uint4*)tmp;
}

// Per (batch, half): half 0 -> K' -> KF frag order; half 1 -> V' -> VF frag order.
__global__ __launch_bounds__(512, 4)
void proj_kv(const float* __restrict__ kv, const float* __restrict__ b_kv,
             const bf16* __restrict__ wkvF, bf16* __restrict__ KF, bf16* __restrict__ VF)
{
    __shared__ __align__(16) char smem[52224];
    bf16* sA = (bf16*)smem;                        // staging [128][200] (51,200 B)
    const int b = blockIdx.x, half = blockIdx.y, t = threadIdx.x;
    const int w = t >> 6, lane = t & 63, quad = lane >> 4, l16 = lane & 15;
    const f32x4 ZV = {0.f, 0.f, 0.f, 0.f};

    for (int f = t; f < 6144; f += 512) {          // 128 rows x 48 float4 fp32->bf16
        const int r = f / 48, c4 = f % 48;
        const float4 v = *(const float4*)&kv[((size_t)b * NKV + r) * CDIM + c4 * 4];
        __align__(8) bf16 tmp[4] = {__float2bfloat16(v.x), __float2bfloat16(v.y),
                                    __float2bfloat16(v.z), __float2bfloat16(v.w)};
        *(uint2*)&sA[r * 200 + c4 * 4] = *(uint2*)tmp;
    }
    __syncthreads();

    f32x4 acc[12];
    #pragma unroll
    for (int i = 0; i < 12; ++i) acc[i] = ZV;
    for (int kk = 0; kk < 6; ++kk) {
        const s16x8 a = *(const s16x8*)&sA[(w * 16 + l16) * 200 + kk * 32 + quad * 8];
        #pragma unroll
        for (int nt = 0; nt < 12; ++nt) {
            const s16x8 bb = *(const s16x8*)&wkvF[(((half * 12 + nt) * 6 + kk) * 64 + lane) * 8];
            acc[nt] = MFMA16(a, bb, acc[nt]);
        }
    }
    __syncthreads();   // sA staging dead; reuse smem as transpose buffer

    if (half == 0) {
        bf16* bufK = (bf16*)smem;                  // K' [128][200]
        #pragma unroll
        for (int nt = 0; nt < 12; ++nt) {
            const int col = nt * 16 + l16;
            const float bias = b_kv[col];
            #pragma unroll
            for (int r = 0; r < 4; ++r)
                bufK[(w * 16 + quad * 4 + r) * 200 + col] = __float2bfloat16(acc[nt][r] + bias);
        }
        __syncthreads();
        bf16* KF_b = KF + (size_t)b * 24576;       // [h][tl8][lane][8]
        #pragma unroll
        for (int i = 0; i < 6; ++i) {              // 6 frags per wave, 48 total
            const int fr = w * 6 + i, h = fr >> 3, tl = fr & 7;
            const s16x8 v = *(const s16x8*)&bufK[(tl * 16 + l16) * 200 + h * DH + quad * 8];
            *(s16x8*)&KF_b[(size_t)(fr * 64 + lane) * 8] = v;
        }
    } else {
        bf16* bufV = (bf16*)smem;                  // V'^T [192][136]
        #pragma unroll
        for (int nt = 0; nt < 12; ++nt) {
            const int d = nt * 16 + l16;
            const float bias = b_kv[CDIM + d];
            __align__(8) bf16 tmp[4];
            #pragma unroll
            for (int r = 0; r < 4; ++r) tmp[r] = __float2bfloat16(acc[nt][r] + bias);
            *(uint2*)&bufV[d * 136 + w * 16 + quad * 4] = *(uint2*)tmp;
        }
        __syncthreads();
        bf16* VF_b = VF + (size_t)b * 24576;       // [h][tl2][kk4][lane][8]
        #pragma unroll
        for (int i = 0; i < 6; ++i) {              // fr = h*8 + tl*4 + kk
            const int fr = w * 6 + i, h = fr >> 3, tl = (fr >> 2) & 1, kk = fr & 3;
            const s16x8 v = *(const s16x8*)&bufV[(h * DH + tl * 16 + l16) * 136 + kk * 32 + quad * 8];
            *(s16x8*)&VF_b[(size_t)(fr * 64 + lane) * 8] = v;
        }
    }
}

// Per (batch, 64-row q chunk): 4 waves, each owning 16 q-rows. All MFMA
// operands are coalesced fragment loads from ws; only LDS use is the
// wave-private 16x136 patch (C-layout <-> A-layout transform).
__global__ __launch_bounds__(256, 6)
void attn_fused(const float* __restrict__ b_q, const float* __restrict__ b_proj,
                const char* __restrict__ wsro, float* __restrict__ out)
{
    __shared__ __align__(16) bf16 sP[4 * 16 * 136];   // 17,408 B
    const int b = blockIdx.x, qc8 = blockIdx.y;
    const int t = threadIdx.x;
    const int w = t >> 6, lane = t & 63, quad = lane >> 4, l16 = lane & 15;
    const int rowblk = qc8 * 4 + w;                   // 0..31
    const f32x4 ZV = {0.f, 0.f, 0.f, 0.f};

    const float* biasM = (const float*)(wsro + OFF_BIAS);
    const bf16*  wqF   = (const bf16*)(wsro + OFF_WQF);
    const bf16*  wpF   = (const bf16*)(wsro + OFF_WPF);
    const bf16*  KF_b  = (const bf16*)(wsro + OFF_KF) + (size_t)b * 24576;
    const bf16*  VF_b  = (const bf16*)(wsro + OFF_VF) + (size_t)b * 24576;
    const bf16*  qF_w  = (const bf16*)(wsro + OFF_QF) + ((size_t)(b * 32 + rowblk) * 3) * 512;

    bf16* myP = sP + w * 16 * 136;

    // q A-fragments for this wave's 16 rows (held across the head loop)
    s16x8 qa[3];
    #pragma unroll
    for (int kk = 0; kk < 3; ++kk)
        qa[kk] = *(const s16x8*)&qF_w[(kk * 64 + lane) * 8];

    f32x4 outacc[6];
    #pragma unroll
    for (int i = 0; i < 6; ++i) outacc[i] = ZV;

    for (int h = 0; h < NH; ++h) {
        // (a) Q'_h = q @ wq_h (pre-scaled) ; + b_q*scale -> patch
        f32x4 qacc[2];
        qacc[0] = ZV; qacc[1] = ZV;
        #pragma unroll
        for (int kk = 0; kk < 3; ++kk) {
            #pragma unroll
            for (int tl = 0; tl < 2; ++tl) {
                const s16x8 bb = *(const s16x8*)&wqF[((((h * 2 + tl) * 3 + kk) * 64) + lane) * 8];
                qacc[tl] = MFMA16(qa[kk], bb, qacc[tl]);
            }
        }
        #pragma unroll
        for (int tl = 0; tl < 2; ++tl) {
            const float bq = b_q[h * DH + tl * 16 + l16] * SCALE;
            #pragma unroll
            for (int r = 0; r < 4; ++r)
                myP[(quad * 4 + r) * 136 + tl * 16 + l16] = __float2bfloat16(qacc[tl][r] + bq);
        }
        __builtin_amdgcn_wave_barrier();

        // (b) S = Q' K'^T  (KF frags coalesced from L2)
        const s16x8 aQ = *(const s16x8*)&myP[l16 * 136 + quad * 8];
        f32x4 sacc[8];
        #pragma unroll
        for (int tl = 0; tl < 8; ++tl) {
            const s16x8 bb = *(const s16x8*)&KF_b[(size_t)((h * 8 + tl) * 64 + lane) * 8];
            sacc[tl] = MFMA16(aQ, bb, ZV);
        }

        // (c) +bias, softmax -> P patch
        #pragma unroll
        for (int r = 0; r < 4; ++r) {
            const int qrow = rowblk * 16 + quad * 4 + r;
            const float* brow = biasM + ((size_t)h * NQ + qrow) * NKV + l16;
            float v[8];
            float mx = -1e30f;
            #pragma unroll
            for (int tl = 0; tl < 8; ++tl) {
                v[tl] = sacc[tl][r] + brow[tl * 16];
                mx = fmaxf(mx, v[tl]);
            }
            #pragma unroll
            for (int off = 1; off < 16; off <<= 1) mx = fmaxf(mx, __shfl_xor(mx, off));
            float sum = 0.f;
            #pragma unroll
            for (int tl = 0; tl < 8; ++tl) { v[tl] = __expf(v[tl] - mx); sum += v[tl]; }
            #pragma unroll
            for (int off = 1; off < 16; off <<= 1) sum += __shfl_xor(sum, off);
            const float inv = 1.f / sum;
            #pragma unroll
            for (int tl = 0; tl < 8; ++tl)
                myP[(quad * 4 + r) * 136 + tl * 16 + l16] = __float2bfloat16(v[tl] * inv);
        }
        __builtin_amdgcn_wave_barrier();

        // (d) O_h = P V'_h  (VF frags coalesced from L2)
        f32x4 oacc[2];
        oacc[0] = ZV; oacc[1] = ZV;
        #pragma unroll
        for (int kk = 0; kk < 4; ++kk) {
            const s16x8 aP = *(const s16x8*)&myP[l16 * 136 + kk * 32 + quad * 8];
            #pragma unroll
            for (int tl = 0; tl < 2; ++tl) {
                const s16x8 bb = *(const s16x8*)&VF_b[(size_t)(((h * 2 + tl) * 4 + kk) * 64 + lane) * 8];
                oacc[tl] = MFMA16(aP, bb, oacc[tl]);
            }
        }
        __builtin_amdgcn_wave_barrier();

        // (e) O_h -> patch ; out += O_h @ wp_h  (register accumulation)
        #pragma unroll
        for (int tl = 0; tl < 2; ++tl)
            #pragma unroll
            for (int r = 0; r < 4; ++r)
                myP[(quad * 4 + r) * 136 + tl * 16 + l16] = __float2bfloat16(oacc[tl][r]);
        __builtin_amdgcn_wave_barrier();

        const s16x8 aO = *(const s16x8*)&myP[l16 * 136 + quad * 8];
        #pragma unroll
        for (int tn = 0; tn < 6; ++tn) {
            const s16x8 bb = *(const s16x8*)&wpF[((h * 6 + tn) * 64 + lane) * 8];
            outacc[tn] = MFMA16(aO, bb, outacc[tn]);
        }
        __builtin_amdgcn_wave_barrier();
    }

    #pragma unroll
    for (int tn = 0; tn < 6; ++tn) {
        const float bp = b_proj[tn * 16 + l16];
        #pragma unroll
        for (int r = 0; r < 4; ++r)
            out[((size_t)b * NQ + rowblk * 16 + quad * 4 + r) * QCDIM + tn * 16 + l16]
                = outacc[tn][r] + bp;
    }
}

extern "C" void kernel_launch(void* const* d_in, const int* in_sizes, int n_in,
                              void* d_out, int out_size, void* d_ws, size_t ws_size,
                              hipStream_t stream)
{
    const float* kv       = (const float*)d_in[0];
    const float* q        = (const float*)d_in[1];
    const float* w_kv     = (const float*)d_in[2];
    const float* b_kv     = (const float*)d_in[3];
    const float* w_q      = (const float*)d_in[4];
    const float* b_q      = (const float*)d_in[5];
    const float* w_proj   = (const float*)d_in[6];
    const float* b_proj   = (const float*)d_in[7];
    const float* bias_tab = (const float*)d_in[8];
    const int*   rel_idx  = (const int*)d_in[9];
    char* ws = (char*)d_ws;

    precomp_bias<<<1536, 256, 0, stream>>>(bias_tab, rel_idx, (float*)(ws + OFF_BIAS));
    precomp_w<<<432, 256, 0, stream>>>(w_kv, w_q, w_proj,
                                       (bf16*)(ws + OFF_WKVF), (bf16*)(ws + OFF_WQF),
                                       (bf16*)(ws + OFF_WPF));
    repack_q<<<6144, 256, 0, stream>>>(q, (bf16*)(ws + OFF_QF));
    proj_kv<<<dim3(B_, 2), 512, 0, stream>>>(kv, b_kv, (const bf16*)(ws + OFF_WKVF),
                                             (bf16*)(ws + OFF_KF), (bf16*)(ws + OFF_VF));
    attn_fused<<<dim3(B_, 8), 256, 0, stream>>>(b_q, b_proj, (const char*)ws, (float*)d_out);
}

// Round 5
// 230.137 us; speedup vs baseline: 1.4920x; 1.2412x over previous
//
#include <hip/hip_runtime.h>
#include <hip/hip_bf16.h>

#define B_    256
#define NKV   128
#define NQ    512
#define CDIM  192
#define QCDIM 96
#define NH    6
#define DH    32
#define SCALE 0.17677669529663687f

typedef __hip_bfloat16 bf16;
typedef __attribute__((ext_vector_type(8))) short s16x8;
typedef __attribute__((ext_vector_type(4))) float f32x4;
#define MFMA16(a, b, c) __builtin_amdgcn_mfma_f32_16x16x32_bf16(a, b, c, 0, 0, 0)

// ---- workspace layout (bytes). *F tensors are MFMA-fragment-ordered:
// [...frag...][lane(64)][elems] so a wave reads one fragment as one coalesced
// 16 B/lane global_load_dwordx4. biasF is in S-output (C-layout) order. ----
#define OFF_BIASF 0                        // fp32 [6][32][8][64][4]     = 1,572,864
#define OFF_WKVF  1572864                  // bf16 [24][6][64][8]        = 147,456
#define OFF_WQF   1720320                  // bf16 [6][2][3][64][8]      = 36,864 (pre-scaled)
#define OFF_WPF   1757184                  // bf16 [6][6][64][8]         = 36,864
#define OFF_KF    1794048                  // bf16 [B_][6][8][64][8]     = 12,582,912
#define OFF_VF    14376960                 // bf16 [B_][6][2][4][64][8]  = 12,582,912
// total 26,959,872 B

// One kernel for all precomputation: biasF (98304 thr) + wkvF/wqF/wpF (110592 thr)
__global__ __launch_bounds__(256)
void precomp_all(const float* __restrict__ w_kv, const float* __restrict__ w_q,
                 const float* __restrict__ w_proj, const float* __restrict__ bias_table,
                 const int* __restrict__ rel_index,
                 float* __restrict__ biasF, bf16* __restrict__ wkvF,
                 bf16* __restrict__ wqF, bf16* __restrict__ wpF)
{
    const int i = blockIdx.x * 256 + threadIdx.x;   // 208896 total
    if (i < 98304) {                                // biasF[h][rowblk][tl][lane][r]
        const int lane = i & 63, tl = (i >> 6) & 7, rowblk = (i >> 9) & 31, h = i >> 14;
        const int quad = lane >> 4, l16 = lane & 15;
        const int kvi = tl * 16 + l16;
        float vr[4];
        #pragma unroll
        for (int r = 0; r < 4; ++r) {
            const int qrow = rowblk * 16 + quad * 4 + r;
            vr[r] = bias_table[rel_index[qrow * NKV + kvi] * NH + h];
        }
        *(float4*)&biasF[i * 4] = make_float4(vr[0], vr[1], vr[2], vr[3]);
    } else if (i < 98304 + 73728) {                 // wkvF[nt24][kk6][lane][j]
        const int i1 = i - 98304;
        const int j = i1 & 7, lane = (i1 >> 3) & 63, kk = (i1 >> 9) % 6, nt = i1 / 3072;
        const int quad = lane >> 4, l16 = lane & 15;
        wkvF[i1] = __float2bfloat16(w_kv[(kk * 32 + quad * 8 + j) * (2 * CDIM) + nt * 16 + l16]);
    } else if (i < 98304 + 92160) {                 // wqF[h][tl2][kk3][lane][j]
        const int i2 = i - 98304 - 73728;
        const int j = i2 & 7, lane = (i2 >> 3) & 63, kk = (i2 >> 9) % 3,
                  tl = (i2 / 1536) & 1, h = i2 / 3072;
        const int quad = lane >> 4, l16 = lane & 15;
        wqF[i2] = __float2bfloat16(w_q[(kk * 32 + quad * 8 + j) * CDIM + h * DH + tl * 16 + l16] * SCALE);
    } else {                                        // wpF[h][tn6][lane][j]
        const int i3 = i - 98304 - 92160;
        const int j = i3 & 7, lane = (i3 >> 3) & 63, tn = (i3 >> 9) % 6, h = i3 / 3072;
        const int quad = lane >> 4, l16 = lane & 15;
        wpF[i3] = __float2bfloat16(w_proj[(h * DH + quad * 8 + j) * QCDIM + tn * 16 + l16]);
    }
}

// Per (batch, half): half 0 -> K' -> KF frag order; half 1 -> V' -> VF frag order.
__global__ __launch_bounds__(512, 4)
void proj_kv(const float* __restrict__ kv, const float* __restrict__ b_kv,
             const bf16* __restrict__ wkvF, bf16* __restrict__ KF, bf16* __restrict__ VF)
{
    __shared__ __align__(16) char smem[52224];
    bf16* sA = (bf16*)smem;                        // staging [128][200]
    const int b = blockIdx.x, half = blockIdx.y, t = threadIdx.x;
    const int w = t >> 6, lane = t & 63, quad = lane >> 4, l16 = lane & 15;
    const f32x4 ZV = {0.f, 0.f, 0.f, 0.f};

    for (int f = t; f < 6144; f += 512) {
        const int r = f / 48, c4 = f % 48;
        const float4 v = *(const float4*)&kv[((size_t)b * NKV + r) * CDIM + c4 * 4];
        __align__(8) bf16 tmp[4] = {__float2bfloat16(v.x), __float2bfloat16(v.y),
                                    __float2bfloat16(v.z), __float2bfloat16(v.w)};
        *(uint2*)&sA[r * 200 + c4 * 4] = *(uint2*)tmp;
    }
    __syncthreads();

    f32x4 acc[12];
    #pragma unroll
    for (int i = 0; i < 12; ++i) acc[i] = ZV;
    for (int kk = 0; kk < 6; ++kk) {
        const s16x8 a = *(const s16x8*)&sA[(w * 16 + l16) * 200 + kk * 32 + quad * 8];
        #pragma unroll
        for (int nt = 0; nt < 12; ++nt) {
            const s16x8 bb = *(const s16x8*)&wkvF[(((half * 12 + nt) * 6 + kk) * 64 + lane) * 8];
            acc[nt] = MFMA16(a, bb, acc[nt]);
        }
    }
    __syncthreads();   // staging dead; reuse smem as transpose buffer

    if (half == 0) {
        bf16* bufK = (bf16*)smem;                  // K' [128][200]
        #pragma unroll
        for (int nt = 0; nt < 12; ++nt) {
            const int col = nt * 16 + l16;
            const float bias = b_kv[col];
            #pragma unroll
            for (int r = 0; r < 4; ++r)
                bufK[(w * 16 + quad * 4 + r) * 200 + col] = __float2bfloat16(acc[nt][r] + bias);
        }
        __syncthreads();
        bf16* KF_b = KF + (size_t)b * 24576;       // [h][tl8][lane][8]
        #pragma unroll
        for (int i = 0; i < 6; ++i) {
            const int fr = w * 6 + i, h = fr >> 3, tl = fr & 7;
            const s16x8 v = *(const s16x8*)&bufK[(tl * 16 + l16) * 200 + h * DH + quad * 8];
            *(s16x8*)&KF_b[(size_t)(fr * 64 + lane) * 8] = v;
        }
    } else {
        bf16* bufV = (bf16*)smem;                  // V'^T [192][136]
        #pragma unroll
        for (int nt = 0; nt < 12; ++nt) {
            const int d = nt * 16 + l16;
            const float bias = b_kv[CDIM + d];
            __align__(8) bf16 tmp[4];
            #pragma unroll
            for (int r = 0; r < 4; ++r) tmp[r] = __float2bfloat16(acc[nt][r] + bias);
            *(uint2*)&bufV[d * 136 + w * 16 + quad * 4] = *(uint2*)tmp;
        }
        __syncthreads();
        bf16* VF_b = VF + (size_t)b * 24576;       // [h][tl2][kk4][lane][8]
        #pragma unroll
        for (int i = 0; i < 6; ++i) {
            const int fr = w * 6 + i, h = fr >> 3, tl = (fr >> 2) & 1, kk = fr & 3;
            const s16x8 v = *(const s16x8*)&bufV[(h * DH + tl * 16 + l16) * 136 + kk * 32 + quad * 8];
            *(s16x8*)&VF_b[(size_t)(fr * 64 + lane) * 8] = v;
        }
    }
}

// Per (batch, 64-row pair-chunk): 4 waves; each wave owns TWO independent
// 16-row chains (ILP). No barriers: patches are wave-private (in-order DS).
__global__ __launch_bounds__(256, 4)
void attn_fused(const float* __restrict__ q, const float* __restrict__ b_q,
                const float* __restrict__ b_proj, const char* __restrict__ wsro,
                float* __restrict__ out)
{
    __shared__ __align__(16) bf16 sP[8 * 16 * 136];   // 34,816 B
    const int b = blockIdx.x, y = blockIdx.y;
    const int t = threadIdx.x;
    const int w = t >> 6, lane = t & 63, quad = lane >> 4, l16 = lane & 15;
    const f32x4 ZV = {0.f, 0.f, 0.f, 0.f};

    const float* biasF = (const float*)(wsro + OFF_BIASF);
    const bf16*  wqF   = (const bf16*)(wsro + OFF_WQF);
    const bf16*  wpF   = (const bf16*)(wsro + OFF_WPF);
    const bf16*  KF_b  = (const bf16*)(wsro + OFF_KF) + (size_t)b * 24576;
    const bf16*  VF_b  = (const bf16*)(wsro + OFF_VF) + (size_t)b * 24576;

    const int rb[2] = { y * 8 + w, y * 8 + w + 4 };   // two row-blocks per wave
    bf16* P0 = sP + (2 * w) * 2176;
    bf16* P1 = sP + (2 * w + 1) * 2176;
    bf16* myP[2] = { P0, P1 };

    // q A-fragments, fp32 -> bf16 in-kernel (no repack kernel)
    s16x8 qa[2][3];
    #pragma unroll
    for (int c = 0; c < 2; ++c)
        #pragma unroll
        for (int kk = 0; kk < 3; ++kk) {
            const float* src = &q[((size_t)b * NQ + rb[c] * 16 + l16) * QCDIM + kk * 32 + quad * 8];
            const float4 a0 = *(const float4*)src;
            const float4 a1 = *(const float4*)(src + 4);
            __align__(16) bf16 tmp[8] = {
                __float2bfloat16(a0.x), __float2bfloat16(a0.y), __float2bfloat16(a0.z),
                __float2bfloat16(a0.w), __float2bfloat16(a1.x), __float2bfloat16(a1.y),
                __float2bfloat16(a1.z), __float2bfloat16(a1.w)};
            qa[c][kk] = *(s16x8*)tmp;
        }

    f32x4 outacc[2][6];
    #pragma unroll
    for (int c = 0; c < 2; ++c)
        #pragma unroll
        for (int i = 0; i < 6; ++i) outacc[c][i] = ZV;

    for (int h = 0; h < NH; ++h) {
        #pragma unroll
        for (int c = 0; c < 2; ++c) {
            // (a) Q'_h = q @ wq_h (pre-scaled) + b_q*scale -> patch
            f32x4 qacc[2];
            qacc[0] = ZV; qacc[1] = ZV;
            #pragma unroll
            for (int kk = 0; kk < 3; ++kk)
                #pragma unroll
                for (int tl = 0; tl < 2; ++tl) {
                    const s16x8 bb = *(const s16x8*)&wqF[(((h * 2 + tl) * 3 + kk) * 64 + lane) * 8];
                    qacc[tl] = MFMA16(qa[c][kk], bb, qacc[tl]);
                }
            #pragma unroll
            for (int tl = 0; tl < 2; ++tl) {
                const float bq = b_q[h * DH + tl * 16 + l16] * SCALE;
                #pragma unroll
                for (int r = 0; r < 4; ++r)
                    myP[c][(quad * 4 + r) * 136 + tl * 16 + l16] = __float2bfloat16(qacc[tl][r] + bq);
            }
            const s16x8 aQ = *(const s16x8*)&myP[c][l16 * 136 + quad * 8];

            // (b) S = Q'K'^T in two 4-tile halves; exp (no max: |score|<1);
            //     unnormalized P -> patch; row-sums accumulated
            float rs[4] = {0.f, 0.f, 0.f, 0.f};
            #pragma unroll
            for (int half = 0; half < 2; ++half) {
                f32x4 sacc[4];
                #pragma unroll
                for (int t4 = 0; t4 < 4; ++t4) {
                    const s16x8 bb = *(const s16x8*)&KF_b[(size_t)((h * 8 + half * 4 + t4) * 64 + lane) * 8];
                    sacc[t4] = MFMA16(aQ, bb, ZV);
                }
                #pragma unroll
                for (int t4 = 0; t4 < 4; ++t4) {
                    const f32x4 b4 = *(const f32x4*)&biasF[(((h * 32 + rb[c]) * 8 + half * 4 + t4) * 64 + lane) * 4];
                    #pragma unroll
                    for (int r = 0; r < 4; ++r) {
                        const float vv = __expf(sacc[t4][r] + b4[r]);
                        rs[r] += vv;
                        myP[c][(quad * 4 + r) * 136 + (half * 4 + t4) * 16 + l16] = __float2bfloat16(vv);
                    }
                }
            }
            float inv[4];
            #pragma unroll
            for (int r = 0; r < 4; ++r) {
                float s = rs[r];
                #pragma unroll
                for (int off = 1; off < 16; off <<= 1) s += __shfl_xor(s, off, 16);
                inv[r] = 1.f / s;
            }

            // (c) O_h = P_unnorm @ V'_h, then scale rows by inv (C row == softmax row)
            f32x4 oacc[2];
            oacc[0] = ZV; oacc[1] = ZV;
            #pragma unroll
            for (int kk = 0; kk < 4; ++kk) {
                const s16x8 aP = *(const s16x8*)&myP[c][l16 * 136 + kk * 32 + quad * 8];
                #pragma unroll
                for (int tl = 0; tl < 2; ++tl) {
                    const s16x8 bb = *(const s16x8*)&VF_b[(size_t)(((h * 2 + tl) * 4 + kk) * 64 + lane) * 8];
                    oacc[tl] = MFMA16(aP, bb, oacc[tl]);
                }
            }
            #pragma unroll
            for (int tl = 0; tl < 2; ++tl)
                #pragma unroll
                for (int r = 0; r < 4; ++r)
                    myP[c][(quad * 4 + r) * 136 + tl * 16 + l16] = __float2bfloat16(oacc[tl][r] * inv[r]);

            // (d) out += O_h @ wp_h (register accumulation)
            const s16x8 aO = *(const s16x8*)&myP[c][l16 * 136 + quad * 8];
            #pragma unroll
            for (int tn = 0; tn < 6; ++tn) {
                const s16x8 bb = *(const s16x8*)&wpF[((h * 6 + tn) * 64 + lane) * 8];
                outacc[c][tn] = MFMA16(aO, bb, outacc[c][tn]);
            }
        }
    }

    #pragma unroll
    for (int c = 0; c < 2; ++c)
        #pragma unroll
        for (int tn = 0; tn < 6; ++tn) {
            const float bp = b_proj[tn * 16 + l16];
            #pragma unroll
            for (int r = 0; r < 4; ++r)
                out[((size_t)b * NQ + rb[c] * 16 + quad * 4 + r) * QCDIM + tn * 16 + l16]
                    = outacc[c][tn][r] + bp;
        }
}

extern "C" void kernel_launch(void* const* d_in, const int* in_sizes, int n_in,
                              void* d_out, int out_size, void* d_ws, size_t ws_size,
                              hipStream_t stream)
{
    const float* kv       = (const float*)d_in[0];
    const float* q        = (const float*)d_in[1];
    const float* w_kv     = (const float*)d_in[2];
    const float* b_kv     = (const float*)d_in[3];
    const float* w_q      = (const float*)d_in[4];
    const float* b_q      = (const float*)d_in[5];
    const float* w_proj   = (const float*)d_in[6];
    const float* b_proj   = (const float*)d_in[7];
    const float* bias_tab = (const float*)d_in[8];
    const int*   rel_idx  = (const int*)d_in[9];
    char* ws = (char*)d_ws;

    precomp_all<<<816, 256, 0, stream>>>(w_kv, w_q, w_proj, bias_tab, rel_idx,
                                         (float*)(ws + OFF_BIASF), (bf16*)(ws + OFF_WKVF),
                                         (bf16*)(ws + OFF_WQF), (bf16*)(ws + OFF_WPF));
    proj_kv<<<dim3(B_, 2), 512, 0, stream>>>(kv, b_kv, (const bf16*)(ws + OFF_WKVF),
                                             (bf16*)(ws + OFF_KF), (bf16*)(ws + OFF_VF));
    attn_fused<<<dim3(B_, 4), 256, 0, stream>>>(q, b_q, b_proj, (const char*)ws,
                                                (float*)d_out);
}